// Round 5
// baseline (390.219 us; speedup 1.0000x reference)
//
#include <hip/hip_runtime.h>
#include <math.h>

constexpr int B  = 128;
constexpr int R  = 4096;
constexpr int IC = 8;
constexpr int C  = 10;
constexpr int O  = 16;

constexpr int RT = 16;           // r's per block (4 waves x 4 r-slots)
constexpr int BT = 4;            // b's per block
constexpr int NRBLK = R / RT;    // 256
constexpr int NBGRP = B / BT;    // 32
constexpr int CO = C * O;        // 160

// DPP butterfly add (VALU pipe, no lgkm wait). ctrl: 0xB1=xor1, 0x4E=xor2,
// 0x140=row_mirror (xor15 within 16-lane row). Template arg => literal const.
template<int CTRL>
__device__ __forceinline__ float dpp_add(float v) {
    return v + __int_as_float(__builtin_amdgcn_update_dpp(
        0, __float_as_int(v), CTRL, 0xF, 0xF, true));
}
// ds_swizzle butterfly add. pat: 0x101F=xor4, 0x401F=xor16 (within 32 lanes).
template<int PAT>
__device__ __forceinline__ float swz_add(float v) {
    return v + __int_as_float(__builtin_amdgcn_ds_swizzle(__float_as_int(v), PAT));
}
// Full 16-lane (o-dim) reduce, all lanes get the sum:
// xor1, xor2, mirror(≡xor12 composed with 1,2), xor4 generate the group.
__device__ __forceinline__ float reduce_o16(float v) {
    v = dpp_add<0xB1>(v);
    v = dpp_add<0x4E>(v);
    v = dpp_add<0x140>(v);
    v = swz_add<0x101F>(v);
    return v;
}

// Pass kernel: thread = (r, o). c-OUTER loop: only W[r,c,o,:] (8 floats,
// pipelined) is live at a time; uh[BT][C] accumulates in registers. No asm
// pins, no W register residency needed. Logits for iter k are uh . vsum
// (vsum = v0+..+v_{k-1}) — agreement is linear in v, no b_ij buffer.
template<int IT>
__global__ __launch_bounds__(256, 4)
void pass_kernel(const float* __restrict__ x, const float* __restrict__ W,
                 const float* __restrict__ vsum, float* __restrict__ s_part)
{
    const int tid  = threadIdx.x;
    const int w    = tid >> 6;
    const int lane = tid & 63;
    const int o    = lane & 15;      // capsule-vector element
    const int rs   = lane >> 4;      // r slot within wave
    const int lr   = w * 4 + rs;     // local r index (0..15)
    const int bgrp = blockIdx.x;     // consecutive blocks share the W slice
    const int rblk = blockIdx.y;
    const int r    = rblk * RT + lr;
    const int b0   = bgrp * BT;

    __shared__ float xL[BT * RT * IC];      // 2 KB
    __shared__ float vL[BT][CO];            // 2.5 KB
    __shared__ float stage[4][BT][CO];      // 10 KB

    // ---- coalesced cooperative x load: 4 b-rows x 512 B ----
    if (tid < 128) {
        const int bb = tid >> 5;
        const int f4 = tid & 31;
        *reinterpret_cast<float4*>(&xL[bb * RT * IC + f4 * 4]) =
            *reinterpret_cast<const float4*>(
                x + ((size_t)(b0 + bb) * R + (size_t)rblk * RT) * IC + f4 * 4);
    }
    if constexpr (IT >= 1) {
        for (int k = tid; k < BT * CO; k += 256)
            (&vL[0][0])[k] = vsum[(size_t)b0 * CO + k];
    }
    __syncthreads();

    // ---- x[b0..b0+3, r, :] into registers (32 floats) ----
    float xv[BT][IC];
    #pragma unroll
    for (int bb = 0; bb < BT; ++bb) {
        float4 xa = *reinterpret_cast<const float4*>(&xL[bb * RT * IC + lr * IC]);
        float4 xb = *reinterpret_cast<const float4*>(&xL[bb * RT * IC + lr * IC + 4]);
        xv[bb][0] = xa.x; xv[bb][1] = xa.y; xv[bb][2] = xa.z; xv[bb][3] = xa.w;
        xv[bb][4] = xb.x; xv[bb][5] = xb.y; xv[bb][6] = xb.z; xv[bb][7] = xb.w;
    }

    // ---- phase 1: uh[bb][c], c-outer so only 2x8 W floats in flight ----
    float uh[BT][C];
    const float* wp = W + (size_t)r * (C * O * IC) + o * IC;
    #pragma unroll 2
    for (int c = 0; c < C; ++c) {
        float4 wa = *reinterpret_cast<const float4*>(wp + c * (O * IC));
        float4 wb = *reinterpret_cast<const float4*>(wp + c * (O * IC) + 4);
        float wr[IC] = {wa.x, wa.y, wa.z, wa.w, wb.x, wb.y, wb.z, wb.w};
        #pragma unroll
        for (int bb = 0; bb < BT; ++bb) {
            float acc = 0.f;
            #pragma unroll
            for (int i = 0; i < IC; ++i) acc = fmaf(wr[i], xv[bb][i], acc);
            uh[bb][c] = acc;
        }
    }

    // ---- phase 2: routing + weighted reduce, per b ----
    #pragma unroll
    for (int bb = 0; bb < BT; ++bb) {
        float t[C];
        if constexpr (IT == 0) {
            #pragma unroll
            for (int c = 0; c < C; ++c) t[c] = 0.1f * uh[bb][c];   // softmax(0)
        } else {
            // logits a[c] = sum_o uh[c,o] * vsum[b,c,o]  (16-lane reduce)
            float a[C];
            #pragma unroll
            for (int c = 0; c < C; ++c) a[c] = uh[bb][c] * vL[bb][c * O + o];
            #pragma unroll
            for (int c = 0; c < C; ++c) a[c] = reduce_o16(a[c]);
            // softmax over c, in-register (redundant across o-lanes = free SIMD)
            float mx = a[0];
            #pragma unroll
            for (int c = 1; c < C; ++c) mx = fmaxf(mx, a[c]);
            float sum = 0.f;
            #pragma unroll
            for (int c = 0; c < C; ++c) { a[c] = __expf(a[c] - mx); sum += a[c]; }
            float inv = 1.f / sum;
            #pragma unroll
            for (int c = 0; c < C; ++c) t[c] = (a[c] * inv) * uh[bb][c];
        }

        // ---- reduce over 4 r-slots (xor32 shfl, xor16 swizzle) ----
        #pragma unroll
        for (int c = 0; c < C; ++c) {
            t[c] += __shfl_xor(t[c], 32, 64);
            t[c] = swz_add<0x401F>(t[c]);
        }

        if (rs == 0) {
            #pragma unroll
            for (int c = 0; c < C; ++c) stage[w][bb][c * O + o] = t[c];
        }
    }

    __syncthreads();

    // ---- epilogue: cross-wave sum, coalesced store ----
    if (tid < CO) {
        #pragma unroll
        for (int bb = 0; bb < BT; ++bb) {
            float s4 = stage[0][bb][tid] + stage[1][bb][tid]
                     + stage[2][bb][tid] + stage[3][bb][tid];
            s_part[((size_t)rblk * B + (b0 + bb)) * CO + tid] = s4;
        }
    }
}

// Sum partials over rblocks, add bias, squash. Block = one (b, c):
// 256 threads = 16 o-lanes x 16 rblk-chunks.
__global__ __launch_bounds__(256)
void reduce_squash(const float* __restrict__ s_part, const float* __restrict__ bias,
                   const float* __restrict__ vin_sum,
                   float* __restrict__ v_out, float* __restrict__ vsum_out)
{
    const int b = blockIdx.x;
    const int c = blockIdx.y;
    const int t = threadIdx.x;
    const int o = t & 15;
    const int q = t >> 4;            // 16 chunks of NRBLK/16 rblocks

    float acc = 0.f;
    for (int k = 0; k < NRBLK / 16; ++k) {
        const int blk = q * (NRBLK / 16) + k;
        acc += s_part[((size_t)blk * B + b) * CO + c * O + o];
    }
    __shared__ float red[16][O];
    red[q][o] = acc;
    __syncthreads();

    if (t < O) {
        float s = bias[c * O + o];
        #pragma unroll
        for (int k = 0; k < 16; ++k) s += red[k][o];
        // ||s||^2 over the 16 o-lanes (all partners active: lanes 0..15)
        float n = reduce_o16(s * s);
        float v = s * sqrtf(n) / (1.f + n);            // squash
        const size_t idx = (size_t)b * CO + c * O + o;
        if (v_out)    v_out[idx] = v;
        if (vsum_out) vsum_out[idx] = (vin_sum ? vin_sum[idx] : 0.f) + v;
    }
}

extern "C" void kernel_launch(void* const* d_in, const int* in_sizes, int n_in,
                              void* d_out, int out_size, void* d_ws, size_t ws_size,
                              hipStream_t stream)
{
    const float* x    = (const float*)d_in[0];
    const float* W    = (const float*)d_in[1];
    const float* bias = (const float*)d_in[2];
    float* out = (float*)d_out;

    float* ws     = (float*)d_ws;
    float* s_part = ws;                                    // NRBLK*B*CO floats (21 MB)
    float* vsumA  = s_part + (size_t)NRBLK * B * CO;       // B*CO floats
    float* vsumB  = vsumA + (size_t)B * CO;                // B*CO floats

    dim3 grid(NBGRP, NRBLK);    // x = b-groups (share W slice), y = r-blocks
    dim3 rg(B, C);

    // iter 0: c = 1/10 uniform
    pass_kernel<0><<<grid, 256, 0, stream>>>(x, W, nullptr, s_part);
    reduce_squash<<<rg, 256, 0, stream>>>(s_part, bias, nullptr, nullptr, vsumA);  // vsumA = v0
    // iter 1: logits = uh . v0
    pass_kernel<1><<<grid, 256, 0, stream>>>(x, W, vsumA, s_part);
    reduce_squash<<<rg, 256, 0, stream>>>(s_part, bias, vsumA, nullptr, vsumB);    // vsumB = v0+v1
    // iter 2: logits = uh . (v0+v1)
    pass_kernel<2><<<grid, 256, 0, stream>>>(x, W, vsumB, s_part);
    reduce_squash<<<rg, 256, 0, stream>>>(s_part, bias, nullptr, out, nullptr);    // out = v2
}

// Round 6
// 208.867 us; speedup vs baseline: 1.8683x; 1.8683x over previous
//
#include <hip/hip_runtime.h>
#include <math.h>

constexpr int B  = 128;
constexpr int R  = 4096;
constexpr int IC = 8;
constexpr int C  = 10;
constexpr int O  = 16;

constexpr int RT = 16;           // r's per block (4 waves x 4 r-slots)
constexpr int BT = 4;            // b's per block
constexpr int NRBLK = R / RT;    // 256
constexpr int NBGRP = B / BT;    // 32
constexpr int CO = C * O;        // 160
constexpr int NXCD = 8;
constexpr int RBLK_PER_XCD = NRBLK / NXCD;   // 32

// DPP butterfly add (VALU pipe). 0xB1=xor1, 0x4E=xor2, 0x140=row_mirror(=xor15).
template<int CTRL>
__device__ __forceinline__ float dpp_add(float v) {
    return v + __int_as_float(__builtin_amdgcn_update_dpp(
        0, __float_as_int(v), CTRL, 0xF, 0xF, true));
}
// ds_swizzle butterfly add. 0x101F=xor4, 0x401F=xor16 (within 32 lanes).
template<int PAT>
__device__ __forceinline__ float swz_add(float v) {
    return v + __int_as_float(__builtin_amdgcn_ds_swizzle(__float_as_int(v), PAT));
}
// Full 16-lane (o-dim) reduce; 3 DPP (VALU) + 1 swizzle (DS).
__device__ __forceinline__ float reduce_o16(float v) {
    v = dpp_add<0xB1>(v);
    v = dpp_add<0x4E>(v);
    v = dpp_add<0x140>(v);
    v = swz_add<0x101F>(v);
    return v;
}

// Pass kernel: thread = (r, o), BT=4 b's per thread. c-loop FULLY unrolled
// (static uh indices -> registers, no scratch). W streamed from L2 once per
// block; XCD-swizzled grid makes each XCD's W+x slice L2-resident.
// Logits for iter k are uh . (v0+..+v_{k-1}) — agreement linear in v.
template<int IT>
__global__ __launch_bounds__(256, 3)
void pass_kernel(const float* __restrict__ x, const float* __restrict__ W,
                 const float* __restrict__ vsum, float* __restrict__ s_part)
{
    const int tid  = threadIdx.x;
    const int w    = tid >> 6;
    const int lane = tid & 63;
    const int o    = lane & 15;      // capsule-vector element
    const int rs   = lane >> 4;      // r slot within wave
    const int lr   = w * 4 + rs;     // local r index (0..15)

    // XCD-aware decode: dispatch round-robins XCDs (g & 7). Give XCD k the
    // contiguous rblk range [32k, 32k+32) so its W slice (2.5 MB) stays in
    // that XCD's L2 across all 32 b-groups.
    const int g    = blockIdx.x;
    const int xcd  = g & (NXCD - 1);
    const int slt  = g >> 3;                       // 0..1023
    const int rblk = xcd * RBLK_PER_XCD + (slt >> 5);
    const int bgrp = slt & 31;
    const int r    = rblk * RT + lr;
    const int b0   = bgrp * BT;

    __shared__ float xL[BT * RT * IC];      // 2 KB
    __shared__ float vL[BT][CO];            // 2.5 KB
    __shared__ float stage[4][BT][CO];      // 10 KB

    // ---- coalesced cooperative x load: 4 b-rows x 512 B ----
    if (tid < 128) {
        const int bb = tid >> 5;
        const int f4 = tid & 31;
        *reinterpret_cast<float4*>(&xL[bb * RT * IC + f4 * 4]) =
            *reinterpret_cast<const float4*>(
                x + ((size_t)(b0 + bb) * R + (size_t)rblk * RT) * IC + f4 * 4);
    }
    if constexpr (IT >= 1) {
        for (int k = tid; k < BT * CO; k += 256)
            (&vL[0][0])[k] = vsum[(size_t)b0 * CO + k];
    }
    __syncthreads();

    // ---- x[b0..b0+3, r, :] into registers (32 floats) ----
    float xv[BT][IC];
    #pragma unroll
    for (int bb = 0; bb < BT; ++bb) {
        float4 xa = *reinterpret_cast<const float4*>(&xL[bb * RT * IC + lr * IC]);
        float4 xb = *reinterpret_cast<const float4*>(&xL[bb * RT * IC + lr * IC + 4]);
        xv[bb][0] = xa.x; xv[bb][1] = xa.y; xv[bb][2] = xa.z; xv[bb][3] = xa.w;
        xv[bb][4] = xb.x; xv[bb][5] = xb.y; xv[bb][6] = xb.z; xv[bb][7] = xb.w;
    }

    // ---- phase 1: uh[bb][c]; c-loop FULLY unrolled, all indices static ----
    float uh[BT][C];
    const float* wp = W + (size_t)r * (C * O * IC) + o * IC;
    #pragma unroll
    for (int c = 0; c < C; ++c) {
        float4 wa = *reinterpret_cast<const float4*>(wp + c * (O * IC));
        float4 wb = *reinterpret_cast<const float4*>(wp + c * (O * IC) + 4);
        const float wr[IC] = {wa.x, wa.y, wa.z, wa.w, wb.x, wb.y, wb.z, wb.w};
        #pragma unroll
        for (int bb = 0; bb < BT; ++bb) {
            float acc = 0.f;
            #pragma unroll
            for (int i = 0; i < IC; ++i) acc = fmaf(wr[i], xv[bb][i], acc);
            uh[bb][c] = acc;
        }
    }

    // ---- phase 2: routing + weighted reduce, per b ----
    #pragma unroll
    for (int bb = 0; bb < BT; ++bb) {
        float t[C];
        if constexpr (IT == 0) {
            #pragma unroll
            for (int c = 0; c < C; ++c) t[c] = 0.1f * uh[bb][c];   // softmax(0)
        } else {
            // logits a[c] = sum_o uh[c,o] * vsum[b,c,o]  (16-lane reduce)
            float a[C];
            #pragma unroll
            for (int c = 0; c < C; ++c) a[c] = uh[bb][c] * vL[bb][c * O + o];
            #pragma unroll
            for (int c = 0; c < C; ++c) a[c] = reduce_o16(a[c]);
            // softmax over c, in-register (redundant across o-lanes)
            float mx = a[0];
            #pragma unroll
            for (int c = 1; c < C; ++c) mx = fmaxf(mx, a[c]);
            float sum = 0.f;
            #pragma unroll
            for (int c = 0; c < C; ++c) { a[c] = __expf(a[c] - mx); sum += a[c]; }
            float inv = 1.f / sum;
            #pragma unroll
            for (int c = 0; c < C; ++c) t[c] = (a[c] * inv) * uh[bb][c];
        }

        // ---- reduce over 4 r-slots (xor32 shfl, xor16 swizzle) ----
        #pragma unroll
        for (int c = 0; c < C; ++c) {
            t[c] += __shfl_xor(t[c], 32, 64);
            t[c] = swz_add<0x401F>(t[c]);
        }

        if (rs == 0) {
            #pragma unroll
            for (int c = 0; c < C; ++c) stage[w][bb][c * O + o] = t[c];
        }
    }

    __syncthreads();

    // ---- epilogue: cross-wave sum, coalesced store ----
    if (tid < CO) {
        #pragma unroll
        for (int bb = 0; bb < BT; ++bb) {
            float s4 = stage[0][bb][tid] + stage[1][bb][tid]
                     + stage[2][bb][tid] + stage[3][bb][tid];
            s_part[((size_t)rblk * B + (b0 + bb)) * CO + tid] = s4;
        }
    }
}

// Sum partials over rblocks, add bias, squash. Block = one (b, c):
// 256 threads = 16 o-lanes x 16 rblk-chunks.
__global__ __launch_bounds__(256)
void reduce_squash(const float* __restrict__ s_part, const float* __restrict__ bias,
                   const float* __restrict__ vin_sum,
                   float* __restrict__ v_out, float* __restrict__ vsum_out)
{
    const int b = blockIdx.x;
    const int c = blockIdx.y;
    const int t = threadIdx.x;
    const int o = t & 15;
    const int q = t >> 4;            // 16 chunks of NRBLK/16 rblocks

    float acc = 0.f;
    for (int k = 0; k < NRBLK / 16; ++k) {
        const int blk = q * (NRBLK / 16) + k;
        acc += s_part[((size_t)blk * B + b) * CO + c * O + o];
    }
    __shared__ float red[16][O];
    red[q][o] = acc;
    __syncthreads();

    if (t < O) {
        float s = bias[c * O + o];
        #pragma unroll
        for (int k = 0; k < 16; ++k) s += red[k][o];
        float n = reduce_o16(s * s);                   // ||s||^2 over o
        float v = s * sqrtf(n) / (1.f + n);            // squash
        const size_t idx = (size_t)b * CO + c * O + o;
        if (v_out)    v_out[idx] = v;
        if (vsum_out) vsum_out[idx] = (vin_sum ? vin_sum[idx] : 0.f) + v;
    }
}

extern "C" void kernel_launch(void* const* d_in, const int* in_sizes, int n_in,
                              void* d_out, int out_size, void* d_ws, size_t ws_size,
                              hipStream_t stream)
{
    const float* x    = (const float*)d_in[0];
    const float* W    = (const float*)d_in[1];
    const float* bias = (const float*)d_in[2];
    float* out = (float*)d_out;

    float* ws     = (float*)d_ws;
    float* s_part = ws;                                    // NRBLK*B*CO floats (21 MB)
    float* vsumA  = s_part + (size_t)NRBLK * B * CO;       // B*CO floats
    float* vsumB  = vsumA + (size_t)B * CO;                // B*CO floats

    dim3 grid(NRBLK * NBGRP);   // 8192, XCD-decoded in-kernel
    dim3 rg(B, C);

    // iter 0: c = 1/10 uniform
    pass_kernel<0><<<grid, 256, 0, stream>>>(x, W, nullptr, s_part);
    reduce_squash<<<rg, 256, 0, stream>>>(s_part, bias, nullptr, nullptr, vsumA);  // vsumA = v0
    // iter 1: logits = uh . v0
    pass_kernel<1><<<grid, 256, 0, stream>>>(x, W, vsumA, s_part);
    reduce_squash<<<rg, 256, 0, stream>>>(s_part, bias, vsumA, nullptr, vsumB);    // vsumB = v0+v1
    // iter 2: logits = uh . (v0+v1)
    pass_kernel<2><<<grid, 256, 0, stream>>>(x, W, vsumB, s_part);
    reduce_squash<<<rg, 256, 0, stream>>>(s_part, bias, nullptr, out, nullptr);    // out = v2
}

// Round 7
// 188.837 us; speedup vs baseline: 2.0664x; 1.1061x over previous
//
#include <hip/hip_runtime.h>
#include <math.h>

constexpr int B  = 128;
constexpr int R  = 4096;
constexpr int IC = 8;
constexpr int C  = 10;
constexpr int O  = 16;

constexpr int RT = 16;           // r's per block (4 waves x 4 r-slots)
constexpr int BT = 4;            // b's per block
constexpr int NRBLK = R / RT;    // 256
constexpr int NBGRP = B / BT;    // 32
constexpr int CO = C * O;        // 160
constexpr int NXCD = 8;
constexpr int RBX = NRBLK / NXCD;   // 32
constexpr int CP = 12;           // c padded to 12 (keeps float4 alignment, 2-way banks)
constexpr int SLOTP = O * CP + 4;   // 196: slot stride, +4 skews banks across slots

// DPP add on the VALU pipe. row_ror:N = 0x120|N rotates within each 16-lane row.
template<int CTRL>
__device__ __forceinline__ float dpp_add(float v) {
    return v + __int_as_float(__builtin_amdgcn_update_dpp(
        0, __float_as_int(v), CTRL, 0xF, 0xF, true));
}
// Sum across a 16-lane row via 4 rotations — every lane gets the total. 0 DS ops.
__device__ __forceinline__ float rowsum16(float v) {
    v = dpp_add<0x121>(v);   // ror:1
    v = dpp_add<0x122>(v);   // ror:2
    v = dpp_add<0x124>(v);   // ror:4
    v = dpp_add<0x128>(v);   // ror:8
    return v;
}

// Pass kernel: thread = (r, o), BT=4 b's per thread. c-loop fully unrolled.
// No in-wave r-slot reduce: every lane writes t[0..9] wide into a skewed LDS
// stage; a per-bb epilogue sums the 16 (wave x rslot) slots. Logits for iter
// k are uh . (v0+..+v_{k-1}) — agreement linear in v.
template<int IT>
__global__ __launch_bounds__(256, 4)
void pass_kernel(const float* __restrict__ x, const float* __restrict__ W,
                 const float* __restrict__ vsum, float* __restrict__ s_part)
{
    const int tid  = threadIdx.x;
    const int w    = tid >> 6;
    const int lane = tid & 63;
    const int o    = lane & 15;      // capsule-vector element
    const int rs   = lane >> 4;      // r slot within wave
    const int lr   = w * 4 + rs;     // local r index (0..15)
    const int slot = tid >> 4;       // 0..15 = (w, rs)

    // XCD-aware decode: XCD k owns rblk [32k, 32k+32) so its W slice stays L2-hot.
    const int g    = blockIdx.x;
    const int xcd  = g & (NXCD - 1);
    const int slt  = g >> 3;
    const int rblk = xcd * RBX + (slt >> 5);
    const int bgrp = slt & 31;
    const int r    = rblk * RT + lr;
    const int b0   = bgrp * BT;

    __shared__ float xL[BT * RT * IC];       // 2 KB
    __shared__ float vT[BT][O][CP];          // 3 KB, transposed v: [bb][o][c]
    __shared__ float stage[2][16 * SLOTP];   // 25 KB, double-buffered per bb

    // ---- coalesced cooperative x load ----
    if (tid < 128) {
        const int bb = tid >> 5;
        const int f4 = tid & 31;
        *reinterpret_cast<float4*>(&xL[bb * RT * IC + f4 * 4]) =
            *reinterpret_cast<const float4*>(
                x + ((size_t)(b0 + bb) * R + (size_t)rblk * RT) * IC + f4 * 4);
    }
    if constexpr (IT >= 1) {
        for (int k = tid; k < BT * CO; k += 256) {
            float val = vsum[(size_t)b0 * CO + k];      // coalesced
            int bb = k / CO; int rem = k - bb * CO;
            vT[bb][rem & 15][rem >> 4] = val;           // transpose into LDS
        }
    }
    __syncthreads();

    // ---- x[b0..b0+3, r, :] into registers ----
    float xv[BT][IC];
    #pragma unroll
    for (int bb = 0; bb < BT; ++bb) {
        float4 xa = *reinterpret_cast<const float4*>(&xL[bb * RT * IC + lr * IC]);
        float4 xb = *reinterpret_cast<const float4*>(&xL[bb * RT * IC + lr * IC + 4]);
        xv[bb][0] = xa.x; xv[bb][1] = xa.y; xv[bb][2] = xa.z; xv[bb][3] = xa.w;
        xv[bb][4] = xb.x; xv[bb][5] = xb.y; xv[bb][6] = xb.z; xv[bb][7] = xb.w;
    }

    // ---- phase 1: uh[bb][c]; fully unrolled ----
    float uh[BT][C];
    const float* wp = W + (size_t)r * (C * O * IC) + o * IC;
    #pragma unroll
    for (int c = 0; c < C; ++c) {
        float4 wa = *reinterpret_cast<const float4*>(wp + c * (O * IC));
        float4 wb = *reinterpret_cast<const float4*>(wp + c * (O * IC) + 4);
        const float wr[IC] = {wa.x, wa.y, wa.z, wa.w, wb.x, wb.y, wb.z, wb.w};
        #pragma unroll
        for (int bb = 0; bb < BT; ++bb) {
            float acc = 0.f;
            #pragma unroll
            for (int i = 0; i < IC; ++i) acc = fmaf(wr[i], xv[bb][i], acc);
            uh[bb][c] = acc;
        }
    }

    // ---- phase 2: routing + stage + per-bb epilogue ----
    #pragma unroll
    for (int bb = 0; bb < BT; ++bb) {
        float t[C];
        if constexpr (IT == 0) {
            #pragma unroll
            for (int c = 0; c < C; ++c) t[c] = 0.1f * uh[bb][c];   // softmax(0)
        } else {
            const float* vb = &vT[bb][o][0];
            float4 va  = *reinterpret_cast<const float4*>(vb);
            float4 vb4 = *reinterpret_cast<const float4*>(vb + 4);
            float2 vc2 = *reinterpret_cast<const float2*>(vb + 8);
            const float vv[C] = {va.x, va.y, va.z, va.w,
                                 vb4.x, vb4.y, vb4.z, vb4.w, vc2.x, vc2.y};
            float a[C];
            #pragma unroll
            for (int c = 0; c < C; ++c) a[c] = uh[bb][c] * vv[c];
            #pragma unroll
            for (int c = 0; c < C; ++c) a[c] = rowsum16(a[c]);     // pure VALU
            // softmax over c without max-subtract: |logit| <= ~6, exp safe
            float sum = 0.f;
            #pragma unroll
            for (int c = 0; c < C; ++c) { a[c] = __expf(a[c]); sum += a[c]; }
            const float inv = __builtin_amdgcn_rcpf(sum);
            #pragma unroll
            for (int c = 0; c < C; ++c) t[c] = (a[c] * inv) * uh[bb][c];
        }

        // ---- wide stage write: every lane, no cross-lane reduce ----
        float* sp = &stage[bb & 1][slot * SLOTP + o * CP];
        *reinterpret_cast<float4*>(sp)     = make_float4(t[0], t[1], t[2], t[3]);
        *reinterpret_cast<float4*>(sp + 4) = make_float4(t[4], t[5], t[6], t[7]);
        *reinterpret_cast<float2*>(sp + 8) = make_float2(t[8], t[9]);
        __syncthreads();

        // ---- epilogue for this bb: sum 16 slots, coalesced global store ----
        if (tid < CO) {
            const int cc = tid >> 4, oo = tid & 15;
            const float* rp = &stage[bb & 1][oo * CP + cc];
            float s = 0.f;
            #pragma unroll
            for (int sl = 0; sl < 16; ++sl) s += rp[sl * SLOTP];
            s_part[((size_t)rblk * B + (b0 + bb)) * CO + tid] = s;
        }
        // next bb writes the other stage buffer; following barrier fences reuse
    }
}

// Sum partials over rblocks, add bias, squash. Block = one (b, c).
__global__ __launch_bounds__(256)
void reduce_squash(const float* __restrict__ s_part, const float* __restrict__ bias,
                   const float* __restrict__ vin_sum,
                   float* __restrict__ v_out, float* __restrict__ vsum_out)
{
    const int b = blockIdx.x;
    const int c = blockIdx.y;
    const int t = threadIdx.x;
    const int o = t & 15;
    const int q = t >> 4;            // 16 chunks of NRBLK/16 rblocks

    float acc = 0.f;
    for (int k = 0; k < NRBLK / 16; ++k) {
        const int blk = q * (NRBLK / 16) + k;
        acc += s_part[((size_t)blk * B + b) * CO + c * O + o];
    }
    __shared__ float red[16][O];
    red[q][o] = acc;
    __syncthreads();

    if (t < O) {
        float s = bias[c * O + o];
        #pragma unroll
        for (int k = 0; k < 16; ++k) s += red[k][o];
        float n = rowsum16(s * s);                     // ||s||^2 over o (lanes 0-15)
        float v = s * sqrtf(n) / (1.f + n);            // squash
        const size_t idx = (size_t)b * CO + c * O + o;
        if (v_out)    v_out[idx] = v;
        if (vsum_out) vsum_out[idx] = (vin_sum ? vin_sum[idx] : 0.f) + v;
    }
}

extern "C" void kernel_launch(void* const* d_in, const int* in_sizes, int n_in,
                              void* d_out, int out_size, void* d_ws, size_t ws_size,
                              hipStream_t stream)
{
    const float* x    = (const float*)d_in[0];
    const float* W    = (const float*)d_in[1];
    const float* bias = (const float*)d_in[2];
    float* out = (float*)d_out;

    float* ws     = (float*)d_ws;
    float* s_part = ws;                                    // NRBLK*B*CO floats (21 MB)
    float* vsumA  = s_part + (size_t)NRBLK * B * CO;       // B*CO floats
    float* vsumB  = vsumA + (size_t)B * CO;                // B*CO floats

    dim3 grid(NRBLK * NBGRP);   // 8192, XCD-decoded in-kernel
    dim3 rg(B, C);

    // iter 0: c = 1/10 uniform
    pass_kernel<0><<<grid, 256, 0, stream>>>(x, W, nullptr, s_part);
    reduce_squash<<<rg, 256, 0, stream>>>(s_part, bias, nullptr, nullptr, vsumA);  // vsumA = v0
    // iter 1: logits = uh . v0
    pass_kernel<1><<<grid, 256, 0, stream>>>(x, W, vsumA, s_part);
    reduce_squash<<<rg, 256, 0, stream>>>(s_part, bias, vsumA, nullptr, vsumB);    // vsumB = v0+v1
    // iter 2: logits = uh . (v0+v1)
    pass_kernel<2><<<grid, 256, 0, stream>>>(x, W, vsumB, s_part);
    reduce_squash<<<rg, 256, 0, stream>>>(s_part, bias, nullptr, out, nullptr);    // out = v2
}

// Round 8
// 103.171 us; speedup vs baseline: 3.7823x; 1.8303x over previous
//
#include <hip/hip_runtime.h>
#include <math.h>

constexpr int B  = 128;
constexpr int R  = 4096;
constexpr int IC = 8;
constexpr int C  = 10;
constexpr int O  = 16;
constexpr int CO = C * O;        // 160

constexpr int RCH    = 16;       // r's per pass block
constexpr int NCHUNK = R / RCH;  // 256

using f16x8 = __attribute__((ext_vector_type(8))) _Float16;   // MFMA A/B frag
using f16x4 = __attribute__((ext_vector_type(4))) _Float16;
using f32x4 = __attribute__((ext_vector_type(4))) float;      // MFMA C/D frag

// DPP add on the VALU pipe. row_ror:N = 0x120|N rotates within each 16-lane row.
template<int CTRL>
__device__ __forceinline__ float dpp_add(float v) {
    return v + __int_as_float(__builtin_amdgcn_update_dpp(
        0, __float_as_int(v), CTRL, 0xF, 0xF, true));
}
__device__ __forceinline__ float rowsum16(float v) {
    v = dpp_add<0x121>(v); v = dpp_add<0x122>(v);
    v = dpp_add<0x124>(v); v = dpp_add<0x128>(v);
    return v;
}

// ---- one-time converts ----
// W fp32 -> fp16, same layout [r][c][o][i]; also writes the 16B zero page.
__global__ __launch_bounds__(256)
void wconv_kernel(const float* __restrict__ W, _Float16* __restrict__ W16,
                  float* __restrict__ zpage)
{
    const size_t i = ((size_t)blockIdx.x * 256 + threadIdx.x) * 4;
    float4 v = *reinterpret_cast<const float4*>(W + i);
    f16x4 h = { (_Float16)v.x, (_Float16)v.y, (_Float16)v.z, (_Float16)v.w };
    *reinterpret_cast<f16x4*>(W16 + i) = h;
    if (blockIdx.x == 0 && threadIdx.x < 4) zpage[threadIdx.x] = 0.f;
}

// x [b][r][i] fp32 -> xT16 [r][b][i] fp16, 16x16 LDS tile transpose.
__global__ __launch_bounds__(256)
void xpose_kernel(const float* __restrict__ x, _Float16* __restrict__ xT16)
{
    __shared__ float tile[16][16][IC + 1];
    const int tid = threadIdx.x;
    const int r0 = blockIdx.x * 16, b0 = blockIdx.y * 16;
    {
        const int rj = tid & 15, bi = tid >> 4;   // coalesced read over r
        const float* src = x + ((size_t)(b0 + bi) * R + (r0 + rj)) * IC;
        float4 a0 = *reinterpret_cast<const float4*>(src);
        float4 a1 = *reinterpret_cast<const float4*>(src + 4);
        float* t = tile[bi][rj];
        t[0]=a0.x; t[1]=a0.y; t[2]=a0.z; t[3]=a0.w;
        t[4]=a1.x; t[5]=a1.y; t[6]=a1.z; t[7]=a1.w;
    }
    __syncthreads();
    {
        const int bi = tid & 15, rj = tid >> 4;   // coalesced write over b
        const float* t = tile[bi][rj];
        f16x8 h;
        #pragma unroll
        for (int i = 0; i < IC; ++i) h[i] = (_Float16)t[i];
        *reinterpret_cast<f16x8*>(xT16 + ((size_t)(r0 + rj) * B + (b0 + bi)) * IC) = h;
    }
}

// ---- MFMA pass ----
// Block = 256 thr = 4 waves; wave = one b-tile (16 b's); block = half of B.
// grid 512, XCD-decoded: XCD k owns chunks [32k,32k+32) (W slice L2-resident);
// the 2 blocks sharing a chunk sit on the same XCD.
// Per r: 10x mfma_f32_16x16x32_f16, A=W[r,c-tile] (16o x 8i, k>=8 zeroed via
// zero-page on B), B=xT[r][b-tile] (8i x 16b). D: row=o (kb*4+reg), col=b.
// Agreement/softmax in-register (v held in 40 VGPRs); sacc accumulates over
// the whole chunk in registers. No LDS, no barriers.
template<int IT>
__global__ __launch_bounds__(256, 3)
void pass_mfma(const _Float16* __restrict__ W16, const _Float16* __restrict__ xT16,
               const float* __restrict__ vsum, const float* __restrict__ zpage,
               float* __restrict__ s_part)
{
    const int tid = threadIdx.x;
    const int wv  = tid >> 6;
    const int l   = tid & 63;
    const int ln  = l & 15;          // A row (o) / B col (b) lane index
    const int kb  = l >> 4;          // k-block: only kb==0 carries real k

    const int g     = blockIdx.x;
    const int xcd   = g & 7;
    const int rest  = g >> 3;
    const int bh    = rest & 1;
    const int cid   = rest >> 1;                  // 0..31
    const int chunk = xcd * 32 + cid;             // 0..255
    const int btile = bh * 4 + wv;                // 0..7
    const int b     = btile * 16 + ln;
    const int r0    = chunk * RCH;

    // per-lane v registers: v[b][c][o = kb*4 + j]
    float vreg[C][4];
    if constexpr (IT >= 1) {
        #pragma unroll
        for (int c = 0; c < C; ++c)
            *reinterpret_cast<float4*>(vreg[c]) =
                *reinterpret_cast<const float4*>(vsum + (size_t)b * CO + c * O + kb * 4);
    }

    f32x4 sacc[C];
    #pragma unroll
    for (int c = 0; c < C; ++c) sacc[c] = (f32x4){0.f, 0.f, 0.f, 0.f};

    const _Float16* xptr = (kb == 0)
        ? (xT16 + ((size_t)r0 * B + b) * IC)
        : reinterpret_cast<const _Float16*>(zpage);
    const ptrdiff_t xstep = (kb == 0) ? (ptrdiff_t)B * IC : 0;
    const _Float16* wptr = W16 + (((size_t)r0 * C) * O + ln) * IC;

    for (int rr = 0; rr < RCH; ++rr) {
        const f16x8 bf = *reinterpret_cast<const f16x8*>(xptr);
        xptr += xstep;

        f32x4 uh[C];
        #pragma unroll
        for (int c = 0; c < C; ++c) {
            f16x8 af = *reinterpret_cast<const f16x8*>(wptr + (size_t)c * (O * IC));
            if constexpr (IT == 0) {
                sacc[c] = __builtin_amdgcn_mfma_f32_16x16x32_f16(af, bf, sacc[c], 0, 0, 0);
            } else {
                uh[c] = __builtin_amdgcn_mfma_f32_16x16x32_f16(
                            af, bf, (f32x4){0.f, 0.f, 0.f, 0.f}, 0, 0, 0);
            }
        }
        wptr += C * O * IC;

        if constexpr (IT >= 1) {
            // logits a[b,c] = sum_o uh*v: 4 in-lane FMA + xor16 + xor32
            float a[C];
            #pragma unroll
            for (int c = 0; c < C; ++c) {
                float p = uh[c][0] * vreg[c][0];
                p = fmaf(uh[c][1], vreg[c][1], p);
                p = fmaf(uh[c][2], vreg[c][2], p);
                p = fmaf(uh[c][3], vreg[c][3], p);
                p += __int_as_float(__builtin_amdgcn_ds_swizzle(__float_as_int(p), 0x401F));
                p += __shfl_xor(p, 32, 64);
                a[c] = p;
            }
            // softmax over c (no max-subtract: |logit| small), rcp divide
            float sum = 0.f;
            #pragma unroll
            for (int c = 0; c < C; ++c) { a[c] = __expf(a[c]); sum += a[c]; }
            const float inv = __builtin_amdgcn_rcpf(sum);
            #pragma unroll
            for (int c = 0; c < C; ++c) {
                const float wgt = a[c] * inv;
                #pragma unroll
                for (int j = 0; j < 4; ++j)
                    sacc[c][j] = fmaf(wgt, uh[c][j], sacc[c][j]);
            }
        }
    }

    constexpr float scale = (IT == 0) ? 0.1f : 1.0f;   // softmax(0) weight
    float* sp = s_part + ((size_t)chunk * B + b) * CO + kb * 4;
    #pragma unroll
    for (int c = 0; c < C; ++c) {
        float4 o4 = make_float4(sacc[c][0] * scale, sacc[c][1] * scale,
                                sacc[c][2] * scale, sacc[c][3] * scale);
        *reinterpret_cast<float4*>(sp + c * O) = o4;
    }
}

// Sum partials over chunks, add bias, squash. Block = one (b, c).
__global__ __launch_bounds__(256)
void reduce_squash(const float* __restrict__ s_part, const float* __restrict__ bias,
                   const float* __restrict__ vin_sum,
                   float* __restrict__ v_out, float* __restrict__ vsum_out)
{
    const int b = blockIdx.x;
    const int c = blockIdx.y;
    const int t = threadIdx.x;
    const int o = t & 15;
    const int q = t >> 4;            // 16 chunks of NCHUNK/16

    float acc = 0.f;
    for (int k = 0; k < NCHUNK / 16; ++k) {
        const int blk = q * (NCHUNK / 16) + k;
        acc += s_part[((size_t)blk * B + b) * CO + c * O + o];
    }
    __shared__ float red[16][O];
    red[q][o] = acc;
    __syncthreads();

    if (t < O) {
        float s = bias[c * O + o];
        #pragma unroll
        for (int k = 0; k < 16; ++k) s += red[k][o];
        float n = rowsum16(s * s);                     // ||s||^2 over o
        float v = s * sqrtf(n) / (1.f + n);            // squash
        const size_t idx = (size_t)b * CO + c * O + o;
        if (v_out)    v_out[idx] = v;
        if (vsum_out) vsum_out[idx] = (vin_sum ? vin_sum[idx] : 0.f) + v;
    }
}

extern "C" void kernel_launch(void* const* d_in, const int* in_sizes, int n_in,
                              void* d_out, int out_size, void* d_ws, size_t ws_size,
                              hipStream_t stream)
{
    const float* x    = (const float*)d_in[0];
    const float* W    = (const float*)d_in[1];
    const float* bias = (const float*)d_in[2];
    float* out = (float*)d_out;

    float* ws     = (float*)d_ws;
    float* s_part = ws;                                     // 256*128*160 = 5,242,880 f
    float* vsumA  = s_part + (size_t)NCHUNK * B * CO;       // 20,480 f
    float* vsumB  = vsumA + (size_t)B * CO;                 // 20,480 f
    float* zpage  = vsumB + (size_t)B * CO;                 // 4 f (16 B zeros)
    _Float16* W16  = (_Float16*)(zpage + 4);                // 5,242,880 halves
    _Float16* xT16 = W16 + (size_t)R * C * O * IC;          // 4,194,304 halves
    // total ~40 MB

    // one-time converts (re-run every call for determinism)
    wconv_kernel<<<(R * C * O * IC) / 1024, 256, 0, stream>>>(W, W16, zpage);
    xpose_kernel<<<dim3(R / 16, B / 16), 256, 0, stream>>>(x, xT16);

    dim3 pg(NCHUNK * 2);     // 512 blocks, XCD-decoded in-kernel
    dim3 rg(B, C);

    // iter 0: weights uniform 0.1 — pure chained MFMA accumulation
    pass_mfma<0><<<pg, 256, 0, stream>>>(W16, xT16, nullptr, zpage, s_part);
    reduce_squash<<<rg, 256, 0, stream>>>(s_part, bias, nullptr, nullptr, vsumA);  // vsumA = v0
    // iter 1: logits = uh . v0
    pass_mfma<1><<<pg, 256, 0, stream>>>(W16, xT16, vsumA, zpage, s_part);
    reduce_squash<<<rg, 256, 0, stream>>>(s_part, bias, vsumA, nullptr, vsumB);    // vsumB = v0+v1
    // iter 2: logits = uh . (v0+v1)
    pass_mfma<2><<<pg, 256, 0, stream>>>(W16, xT16, vsumB, zpage, s_part);
    reduce_squash<<<rg, 256, 0, stream>>>(s_part, bias, nullptr, out, nullptr);    // out = v2
}